// Round 15
// baseline (195.457 us; speedup 1.0000x reference)
//
#include <hip/hip_runtime.h>
#include <hip/hip_bf16.h>

// Problem constants
#define B_   2
#define N_   2048
#define D_   128
#define H_   16
#define ALL_ 2048
#define M_   (B_*N_)    // 4096 total rows
#define BH_  (B_*H_)    // 32 (batch*heads)

typedef __bf16 bf16;
typedef __bf16 bf16x8 __attribute__((ext_vector_type(8)));
typedef __bf16 bf16x4 __attribute__((ext_vector_type(4)));
typedef float  floatx4 __attribute__((ext_vector_type(4)));

#define MFMA32K(a,b,c) __builtin_amdgcn_mfma_f32_16x16x32_bf16((a),(b),(c),0,0,0)

// async global->LDS DMA, 16B per lane (m97 pattern).
// Global address is PER-LANE (base + lane*8 bf16); LDS addr wave-uniform.
__device__ inline void load_lds16(const bf16* g, bf16* l) {
    __builtin_amdgcn_global_load_lds((const __attribute__((address_space(1))) void*)g,
                                     (__attribute__((address_space(3))) void*)l, 16, 0, 0);
}

#define WAITCNT_VM(n) ((0xF << 8) | (0x7 << 4) | (n))

// ---------------------------------------------------------------------------
// FRAGMENT-MAJOR LAYOUTS (unchanged from R14):
//  Wf  (Wq/Wk/Wv): [ct 128][kf 4][lane][8]   Wof: [ct 8][kf 64][lane][8]
//  xf:  [rt 256][kf 4][lane][8]               Qf/Kf: [bh][t 128][kf 4][lane][8]
//  Vf:  [bh][kb 32][nf 8][g 2][lane][8]
//  ctxf: TWO slots [half][qt 256][kf 64][lane][8] (raw per-half O numerators;
//        reduce() folds (O0+O1)*rl in place into slot 0 for out_proj)
//  lbuf: fp32 [half 2][bh 32][q 2048] softmax denominators
// ---------------------------------------------------------------------------

// ---------------------------------------------------------------------------
// Kernel T: prep (unchanged from R14).
// ---------------------------------------------------------------------------
__global__ __launch_bounds__(256) void prep_weights(const float* __restrict__ x,
                                                    const float* __restrict__ Wq,
                                                    const float* __restrict__ Wk,
                                                    const float* __restrict__ Wv,
                                                    const float* __restrict__ Wo,
                                                    const int* __restrict__ mask,
                                                    bf16* __restrict__ Wqf,
                                                    bf16* __restrict__ Wkf,
                                                    bf16* __restrict__ Wvf,
                                                    bf16* __restrict__ Wof,
                                                    bf16* __restrict__ xf,
                                                    float* __restrict__ mbias) {
    __shared__ bf16 pw[16896];
    int bid = blockIdx.x, t = threadIdx.x;
    int lane = t & 63, wave = t >> 6;
    int lrow = lane & 15, quad = lane >> 4;

    if (bid < 96) {
        int m = bid >> 5, cg = bid & 31;
        const float* W = (m == 0) ? Wq : (m == 1) ? Wk : Wv;
        bf16* Wf       = (m == 0) ? Wqf : (m == 1) ? Wkf : Wvf;
        int slot = t & 15, rowb = t >> 4;
#pragma unroll
        for (int i = 0; i < 8; i++) {
            int r = rowb + i * 16;
            float4 v = *(const float4*)(W + (size_t)r * 2048 + cg * 64 + slot * 4);
            bf16x4 o; o[0]=(bf16)v.x; o[1]=(bf16)v.y; o[2]=(bf16)v.z; o[3]=(bf16)v.w;
            *(bf16x4*)(&pw[r * 68 + slot * 4]) = o;
        }
        __syncthreads();
        int ctl = wave;
#pragma unroll
        for (int kf = 0; kf < 4; kf++) {
            bf16x8 w;
#pragma unroll
            for (int j = 0; j < 8; j++) w[j] = pw[(kf * 32 + quad * 8 + j) * 68 + ctl * 16 + lrow];
            *(bf16x8*)(Wf + (size_t)((cg * 4 + ctl) * 4 + kf) * 512 + lane * 8) = w;
        }
    } else if (bid < 112) {
        int kb16 = bid - 96, k0 = kb16 * 128;
        int slot = t & 31, rowb = t >> 5;
#pragma unroll
        for (int i = 0; i < 16; i++) {
            int r = rowb + i * 8;
            float4 v = *(const float4*)(Wo + (size_t)(k0 + r) * 128 + slot * 4);
            bf16x4 o; o[0]=(bf16)v.x; o[1]=(bf16)v.y; o[2]=(bf16)v.z; o[3]=(bf16)v.w;
            *(bf16x4*)(&pw[r * 132 + slot * 4]) = o;
        }
        __syncthreads();
        int kfl = wave;
#pragma unroll
        for (int ct = 0; ct < 8; ct++) {
            bf16x8 w;
#pragma unroll
            for (int j = 0; j < 8; j++) w[j] = pw[(kfl * 32 + quad * 8 + j) * 132 + ct * 16 + lrow];
            *(bf16x8*)(Wof + (size_t)(ct * 64 + kb16 * 4 + kfl) * 512 + lane * 8) = w;
        }
    } else if (bid < 176) {
        int rg = bid - 112, r0 = rg * 64;
        int slot = t & 31, rowb = t >> 5;
#pragma unroll
        for (int i = 0; i < 8; i++) {
            int r = rowb + i * 8;
            float4 v = *(const float4*)(x + (size_t)(r0 + r) * 128 + slot * 4);
            bf16x4 o; o[0]=(bf16)v.x; o[1]=(bf16)v.y; o[2]=(bf16)v.z; o[3]=(bf16)v.w;
            *(bf16x4*)(&pw[r * 136 + slot * 4]) = o;
        }
        __syncthreads();
        int rtl = wave;
#pragma unroll
        for (int kf = 0; kf < 4; kf++) {
            bf16x8 w = *(const bf16x8*)(&pw[(rtl * 16 + lrow) * 136 + kf * 32 + quad * 8]);
            *(bf16x8*)(xf + (size_t)((rg * 4 + rtl) * 4 + kf) * 512 + lane * 8) = w;
        }
    } else {
        int e = (bid - 176) * 256 + t;
        mbias[e] = mask[e] ? 0.0f : -30.0f;
    }
}

// ---------------------------------------------------------------------------
// Kernel A: Q/K/V projection (unchanged from R14, grid (64,32,3)).
// ---------------------------------------------------------------------------
__global__ __launch_bounds__(256) void qkv_proj(const bf16* __restrict__ xf,
                                                const float* __restrict__ bq,
                                                const float* __restrict__ bk,
                                                const float* __restrict__ bv,
                                                const bf16* __restrict__ Wqf,
                                                const bf16* __restrict__ Wkf,
                                                const bf16* __restrict__ Wvf,
                                                bf16* __restrict__ Qf,
                                                bf16* __restrict__ Kf,
                                                bf16* __restrict__ Vf) {
    __shared__ bf16 tile[64][72];

    int z = blockIdx.z;
    const float* bias = (z == 0) ? bq : (z == 1) ? bk : bv;
    const bf16*  Wf   = (z == 0) ? Wqf : (z == 1) ? Wkf : Wvf;

    int tid = threadIdx.x;
    int wave = tid >> 6, lane = tid & 63;
    int lrow = lane & 15, quad = lane >> 4;
    int r0b = blockIdx.x * 64;
    int c0 = blockIdx.y * 64;
    int cg4 = c0 >> 4;

    int rt = (r0b >> 4) + wave;
    bf16x8 a[4];
#pragma unroll
    for (int kf = 0; kf < 4; kf++)
        a[kf] = *(const bf16x8*)(xf + (size_t)(rt * 4 + kf) * 512 + lane * 8);

    int bb = r0b >> 11;
    int h  = c0 >> 7;
    int bhw = bb * 16 + h;
    int tile16 = (r0b & 2047) >> 4;
    int kbt = (r0b & 2047) >> 6;
    floatx4 zero4 = {0.f, 0.f, 0.f, 0.f};

    floatx4 acc[4] = {zero4, zero4, zero4, zero4};
#pragma unroll
    for (int kf = 0; kf < 4; kf++) {
#pragma unroll
        for (int nf = 0; nf < 4; nf++) {
            bf16x8 b = *(const bf16x8*)(Wf + (size_t)((cg4 + nf) * 4 + kf) * 512 + lane * 8);
            acc[nf] = MFMA32K(a[kf], b, acc[nf]);
        }
    }

#pragma unroll
    for (int nf = 0; nf < 4; nf++) {
        int col = nf * 16 + lrow;
        float bvv = bias[c0 + col];
#pragma unroll
        for (int r = 0; r < 4; r++) {
            int row = wave * 16 + quad * 4 + r;
            bf16 val = (bf16)(acc[nf][r] + bvv);
            if (z < 2) tile[row][col] = val;
            else       tile[col][row] = val;
        }
    }
    __syncthreads();

    if (z < 2) {
        bf16* dst = (z == 0) ? Qf : Kf;
        int s = wave;
        int kfbase = (c0 & 127) >> 5;
        size_t fbase = ((size_t)bhw * 128 + tile16 + s) * 4 + kfbase;
#pragma unroll
        for (int kfl = 0; kfl < 2; kfl++) {
            bf16x8 w = *(const bf16x8*)(&tile[s * 16 + lrow][kfl * 32 + quad * 8]);
            *(bf16x8*)(dst + (fbase + kfl) * 512 + lane * 8) = w;
        }
    } else {
        int nfl = wave;
        int nfbase = (c0 & 127) >> 4;
        size_t fbase = (((size_t)bhw * 32 + kbt) * 8 + (nfbase + nfl)) * 2;
#pragma unroll
        for (int g = 0; g < 2; g++) {
            bf16x4 a0 = *(const bf16x4*)(&tile[nfl * 16 + lrow][g * 32 + quad * 4]);
            bf16x4 a1 = *(const bf16x4*)(&tile[nfl * 16 + lrow][g * 32 + 16 + quad * 4]);
            bf16x8 w;
            w[0]=a0[0]; w[1]=a0[1]; w[2]=a0[2]; w[3]=a0[3];
            w[4]=a1[0]; w[5]=a1[1]; w[6]=a1[2]; w[7]=a1[3];
            *(bf16x8*)(Vf + (fbase + g) * 512 + lane * 8) = w;
        }
    }
}

// ---------------------------------------------------------------------------
// Kernel B: flash attention, SPLIT-K over key-halves (exact: no running max,
// so O = (O0+O1)/(l0+l1) combines bit-correctly). Grid 1024 = 2x blocks ->
// LDS cut 72->52KB (K dbuf 32 + V single 16 + mbias-half 4) gives 3
// blocks/CU = 12 waves/CU (+50% occupancy vs the pinned 8 of R14).
// K keeps its prefetch pipeline (first-consumed operand); V's refill DMA is
// issued after the post-PV barrier and its exposure is covered by the extra
// resident blocks. Writes RAW numerator O (bf16) to ctxf slot[half] and l
// to lbuf; reduce() normalizes.
// ---------------------------------------------------------------------------
__global__ __launch_bounds__(256) void flash_attn(const bf16* __restrict__ Qf,
                                                  const bf16* __restrict__ Kf,
                                                  const bf16* __restrict__ Vf,
                                                  const float* __restrict__ mbias,
                                                  bf16* __restrict__ ctxf,
                                                  float* __restrict__ lbuf) {
    __shared__ bf16 sm[26624];   // [0,16384): K dbuf; [16384,24576): V buf;
                                 // [24576,26624): mbias half-row (1024 f32)
    float* mbL = (float*)&sm[24576];

    int tid = threadIdx.x;
    int wave = tid >> 6, lane = tid & 63;
    int lrow = lane & 15, quad = lane >> 4;
    // XCD swizzle: 1024 blocks = 8 xcd * (4 bh * 16 qblk * 2 half)
    int bid = blockIdx.x;
    int xcd = bid & 7, seq = bid >> 3;          // seq 0..127
    int bh  = xcd * 4 + (seq >> 5);             // 0..31
    int rem = seq & 31;
    int qblk = rem >> 1;                        // 0..15
    int half = rem & 1;                         // key-half
    int b  = bh >> 4;
    int q0 = qblk * 128 + wave * 32;
    int kb0 = half * 16;

    const float* mbp = mbias + b * N_ + half * 1024;
    const bf16* kbase = Kf + ((size_t)bh * 32 + kb0) * 8192;
    const bf16* vbase = Vf + ((size_t)bh * 32 + kb0) * 8192;

    // Q B-frags (coalesced), held all loop
    bf16x8 qf[2][4];
#pragma unroll
    for (int u = 0; u < 2; u++)
#pragma unroll
        for (int kf = 0; kf < 4; kf++)
            qf[u][kf] = *(const bf16x8*)(Qf + (size_t)(((size_t)bh * 128 + (q0 >> 4) + u) * 4 + kf) * 512 + lane * 8);

    bf16x8 ones;
#pragma unroll
    for (int j = 0; j < 8; j++) ones[j] = (bf16)1.0f;

    floatx4 zero4 = {0.f, 0.f, 0.f, 0.f};
    floatx4 O[2][8];
#pragma unroll
    for (int u = 0; u < 2; u++)
#pragma unroll
        for (int nf = 0; nf < 8; nf++) O[u][nf] = zero4;
    floatx4 Oext[2] = {zero4, zero4};   // l row-sums via ones-MFMA

    const float scale = 0.0883883476483184f;   // 1/sqrt(128)

    // ---- prologue: K(0)->buf0, V(0)->Vbuf, mbias half-row -> LDS ----
#pragma unroll
    for (int i = 0; i < 4; i++) {
        int seg = wave * 4 + i;                // 0..15, 1KB each
        load_lds16(kbase + seg * 512 + lane * 8, &sm[seg * 512]);
        load_lds16(vbase + seg * 512 + lane * 8, &sm[16384 + seg * 512]);
    }
    load_lds16((const bf16*)(mbp + wave * 256) + lane * 8, (bf16*)(mbL + wave * 256));

    for (int kbl = 0; kbl < 16; kbl++) {
        int kcur = (kbl & 1) << 13;            // 0 or 8192

        // ---- wait my DMA(kbl) [K+V(+mb)], block-wide visibility ----
        __builtin_amdgcn_s_waitcnt(WAITCNT_VM(0));
        __builtin_amdgcn_s_barrier();

        // ---- prefetch K(kbl+1) into the other K buffer ----
        if (kbl < 15) {
            int nxt = kcur ^ 8192;
            const bf16* ksrc = kbase + (size_t)(kbl + 1) * 8192;
#pragma unroll
            for (int i = 0; i < 4; i++) {
                int seg = wave * 4 + i;
                load_lds16(ksrc + seg * 512 + lane * 8, &sm[nxt + seg * 512]);
            }
        }

        // ---- S^T per 16-key tile; exp; pack into K=32 B-frags ----
        bf16x8 pf[2][2];
#pragma unroll
        for (int s = 0; s < 4; s++) {
            floatx4 S0 = zero4, S1 = zero4;
#pragma unroll
            for (int kf = 0; kf < 4; kf++) {
                bf16x8 kfr = *(const bf16x8*)(&sm[kcur + ((s * 4 + kf) * 64 + lane) * 8]);
                S0 = MFMA32K(kfr, qf[0][kf], S0);
                S1 = MFMA32K(kfr, qf[1][kf], S1);
            }
            float4 mb4 = *(const float4*)(mbL + kbl * 64 + s * 16 + quad * 4);
            const float* mbr = (const float*)&mb4;
            int g = s >> 1, o = (s & 1) * 4;
#pragma unroll
            for (int r = 0; r < 4; r++) {
                float p0 = __expf(fmaf(S0[r], scale, mbr[r]));
                float p1 = __expf(fmaf(S1[r], scale, mbr[r]));
                pf[0][g][o + r] = (bf16)p0;
                pf[1][g][o + r] = (bf16)p1;
            }
        }

        // ---- l row-sums via ones-MFMA ----
#pragma unroll
        for (int g = 0; g < 2; g++) {
            Oext[0] = MFMA32K(ones, pf[0][g], Oext[0]);
            Oext[1] = MFMA32K(ones, pf[1][g], Oext[1]);
        }

        // ---- PV from the single V buffer ----
#pragma unroll
        for (int nf = 0; nf < 8; nf++) {
#pragma unroll
            for (int g = 0; g < 2; g++) {
                bf16x8 vfr = *(const bf16x8*)(&sm[16384 + ((nf * 2 + g) * 64 + lane) * 8]);
                O[0][nf] = MFMA32K(vfr, pf[0][g], O[0][nf]);
                O[1][nf] = MFMA32K(vfr, pf[1][g], O[1][nf]);
            }
        }

        // ---- all waves done reading V buf -> refill it for kbl+1 ----
        if (kbl < 15) {
            __builtin_amdgcn_s_barrier();
            const bf16* vsrc = vbase + (size_t)(kbl + 1) * 8192;
#pragma unroll
            for (int i = 0; i < 4; i++) {
                int seg = wave * 4 + i;
                load_lds16(vsrc + seg * 512 + lane * 8, &sm[16384 + seg * 512]);
            }
        }
    }

    // ---- epilogue: store l; raw O -> bf16 -> frag reshape -> ctxf[half] ----
    __syncthreads();                    // drain before reusing sm
    int wb = wave * 4352;               // 32 rows * 136 stride per wave
#pragma unroll
    for (int u = 0; u < 2; u++) {
        int q = q0 + u * 16 + lrow;
        if (quad == 0)
            lbuf[((size_t)half * 32 + bh) * 2048 + q] = Oext[u][0];
#pragma unroll
        for (int nf = 0; nf < 8; nf++) {
            bf16x4 o;
#pragma unroll
            for (int j = 0; j < 4; j++) o[j] = (bf16)O[u][nf][j];
            *(bf16x4*)(&sm[wb + (u * 16 + lrow) * 136 + nf * 16 + quad * 4]) = o;
        }
    }
    __syncthreads();
    int h4 = (bh & 15) * 4;
    size_t qtb = (size_t)b * 128 + (q0 >> 4);
    bf16* ctx_h = ctxf + (size_t)half * M_ * ALL_;
#pragma unroll
    for (int u = 0; u < 2; u++) {
#pragma unroll
        for (int kfl = 0; kfl < 4; kfl++) {
            bf16x8 w = *(const bf16x8*)(&sm[wb + (u * 16 + lrow) * 136 + kfl * 32 + quad * 8]);
            *(bf16x8*)(ctx_h + ((qtb + u) * 64 + h4 + kfl) * 512 + lane * 8) = w;
        }
    }
}

// ---------------------------------------------------------------------------
// Kernel R: reduce halves: slot0 = (slot0 + slot1) * rl, in place, where
// rl = qmask && (l0+l1)>0 ? 1/(l0+l1) : 0 (per q-row & head). Coalesced
// bf16x8; frag decode gives q = qt*16+(lane&15), head = kf>>2.
// ---------------------------------------------------------------------------
__global__ __launch_bounds__(256) void reduce_halves(bf16* __restrict__ ctxf,
                                                     const float* __restrict__ lbuf,
                                                     const int* __restrict__ mask) {
    const size_t slot = (size_t)M_ * ALL_;
    int t = blockIdx.x * 256 + threadIdx.x;
#pragma unroll
    for (int it = 0; it < 2; it++) {
        int u8 = it * 524288 + t;              // 8-elem unit, 0..1048575
        int lane = u8 & 63;
        int kf   = (u8 >> 6) & 63;
        int qt   = u8 >> 12;                   // 0..255
        int lrow = lane & 15;
        int b  = qt >> 7;
        int qn = (qt & 127) * 16 + lrow;
        int head = kf >> 2;
        float l0 = lbuf[((size_t)0 * 32 + b * 16 + head) * 2048 + qn];
        float l1 = lbuf[((size_t)1 * 32 + b * 16 + head) * 2048 + qn];
        int qm = mask[b * N_ + qn];
        float ls = l0 + l1;
        float rl = (qm && ls > 0.f) ? (1.0f / ls) : 0.f;
        size_t off = (size_t)u8 * 8;
        bf16x8 a0 = *(const bf16x8*)(ctxf + off);
        bf16x8 a1 = *(const bf16x8*)(ctxf + slot + off);
        bf16x8 w;
#pragma unroll
        for (int j = 0; j < 8; j++)
            w[j] = (bf16)(((float)a0[j] + (float)a1[j]) * rl);
        *(bf16x8*)(ctxf + off) = w;
    }
}

// ---------------------------------------------------------------------------
// Kernel C: out_proj (unchanged from R14; reads normalized ctxf slot 0).
// ---------------------------------------------------------------------------
__global__ __launch_bounds__(128) void out_proj(const bf16* __restrict__ ctxf,
                                                const bf16* __restrict__ Wof,
                                                const float* __restrict__ bo,
                                                float* __restrict__ out) {
    __shared__ float red[512];
    int tid = threadIdx.x;
    int wave = tid >> 6, lane = tid & 63;
    int lrow = lane & 15, quad = lane >> 4;
    int qt = blockIdx.x;
    int ct = blockIdx.y * 2;
    int r0 = qt * 16, c0 = ct * 16;

    floatx4 zero4 = {0.f, 0.f, 0.f, 0.f};
    floatx4 acc[2] = {zero4, zero4};
    const bf16* ap = ctxf + ((size_t)qt * 64 + wave * 32) * 512 + lane * 8;
    const bf16* b0 = Wof + ((size_t)ct * 64 + wave * 32) * 512 + lane * 8;
    const bf16* b1 = b0 + (size_t)64 * 512;
#pragma unroll 4
    for (int kf = 0; kf < 32; kf++) {
        bf16x8 a  = *(const bf16x8*)(ap + (size_t)kf * 512);
        bf16x8 w0 = *(const bf16x8*)(b0 + (size_t)kf * 512);
        bf16x8 w1 = *(const bf16x8*)(b1 + (size_t)kf * 512);
        acc[0] = MFMA32K(a, w0, acc[0]);
        acc[1] = MFMA32K(a, w1, acc[1]);
    }
    if (wave == 1) {
#pragma unroll
        for (int nf = 0; nf < 2; nf++)
#pragma unroll
            for (int r = 0; r < 4; r++)
                red[nf * 256 + r * 64 + lane] = acc[nf][r];
    }
    __syncthreads();
    if (wave == 0) {
#pragma unroll
        for (int nf = 0; nf < 2; nf++) {
            int col = c0 + nf * 16 + lrow;
            float bv = bo[col];
#pragma unroll
            for (int r = 0; r < 4; r++) {
                int m = r0 + quad * 4 + r;
                out[(size_t)m * 128 + col] = acc[nf][r] + red[nf * 256 + r * 64 + lane] + bv;
            }
        }
    }
}

// ---------------------------------------------------------------------------
extern "C" void kernel_launch(void* const* d_in, const int* in_sizes, int n_in,
                              void* d_out, int out_size, void* d_ws, size_t ws_size,
                              hipStream_t stream) {
    const float* x    = (const float*)d_in[0];
    const int*   mask = (const int*)d_in[1];
    const float* Wq   = (const float*)d_in[2];
    const float* bq   = (const float*)d_in[3];
    const float* Wk   = (const float*)d_in[4];
    const float* bk   = (const float*)d_in[5];
    const float* Wv   = (const float*)d_in[6];
    const float* bv   = (const float*)d_in[7];
    const float* Wo   = (const float*)d_in[8];
    const float* bo   = (const float*)d_in[9];
    float* out = (float*)d_out;

    char* ws = (char*)d_ws;
    size_t off = 0;
    bf16* Wqf = (bf16*)(ws + off); off += (size_t)262144 * 2;
    bf16* Wkf = (bf16*)(ws + off); off += (size_t)262144 * 2;
    bf16* Wvf = (bf16*)(ws + off); off += (size_t)262144 * 2;
    bf16* Wof = (bf16*)(ws + off); off += (size_t)262144 * 2;
    bf16* xf  = (bf16*)(ws + off); off += (size_t)524288 * 2;
    size_t qkv_elems = (size_t)BH_ * N_ * 128;            // 8.4M
    bf16* Qf  = (bf16*)(ws + off); off += qkv_elems * 2;  // fragment-major
    bf16* Kf  = (bf16*)(ws + off); off += qkv_elems * 2;
    bf16* Vf  = (bf16*)(ws + off); off += qkv_elems * 2;
    bf16* ctxf = (bf16*)(ws + off); off += (size_t)2 * M_ * ALL_ * 2;  // 2 slots
    float* lbuf = (float*)(ws + off); off += (size_t)2 * 32 * 2048 * 4;
    float* mbias = (float*)(ws + off); off += (size_t)B_ * N_ * 4;
    (void)ws_size; (void)in_sizes; (void)n_in; (void)out_size;

    prep_weights<<<192, 256, 0, stream>>>(x, Wq, Wk, Wv, Wo, mask,
                                          Wqf, Wkf, Wvf, Wof, xf, mbias);

    qkv_proj<<<dim3(64, 32, 3), 256, 0, stream>>>(xf, bq, bk, bv, Wqf, Wkf, Wvf,
                                                  Qf, Kf, Vf);

    flash_attn<<<1024, 256, 0, stream>>>(Qf, Kf, Vf, mbias, ctxf, lbuf);

    reduce_halves<<<2048, 256, 0, stream>>>(ctxf, lbuf, mask);

    out_proj<<<dim3(256, 4), 128, 0, stream>>>(ctxf, Wof, bo, out);
}

// Round 16
// 181.677 us; speedup vs baseline: 1.0759x; 1.0759x over previous
//
#include <hip/hip_runtime.h>
#include <hip/hip_bf16.h>

// Problem constants
#define B_   2
#define N_   2048
#define D_   128
#define H_   16
#define ALL_ 2048
#define M_   (B_*N_)    // 4096 total rows
#define BH_  (B_*H_)    // 32 (batch*heads)

typedef __bf16 bf16;
typedef __bf16 bf16x8 __attribute__((ext_vector_type(8)));
typedef __bf16 bf16x4 __attribute__((ext_vector_type(4)));
typedef float  floatx4 __attribute__((ext_vector_type(4)));

#define MFMA32K(a,b,c) __builtin_amdgcn_mfma_f32_16x16x32_bf16((a),(b),(c),0,0,0)

// async global->LDS DMA, 16B per lane (m97 pattern).
// Global address is PER-LANE (base + lane*8 bf16); LDS addr wave-uniform.
__device__ inline void load_lds16(const bf16* g, bf16* l) {
    __builtin_amdgcn_global_load_lds((const __attribute__((address_space(1))) void*)g,
                                     (__attribute__((address_space(3))) void*)l, 16, 0, 0);
}

#define WAITCNT_VM(n) ((0xF << 8) | (0x7 << 4) | (n))

// ---------------------------------------------------------------------------
// FRAGMENT-MAJOR LAYOUTS (all global tensors MFMA-fragment-major so every
// global access in every kernel is lane*16B contiguous):
//  A/B-frag convention (16x16x32): elem j of lane (lrow=lane&15,quad=lane>>4)
//    A[m=lrow][k=kf*32+quad*8+j]  /  B[k=kf*32+quad*8+j][n=lrow]
//  Wf  (Wq/Wk/Wv): [ct 128][kf 4][lane][8]   Wof: [ct 8][kf 64][lane][8]
//  xf:  [rt 256][kf 4][lane][8]               Qf/Kf: [bh][t 128][kf 4][lane][8]
//  Vf:  [bh][kb 32][nf 8][g 2][lane][8]
//  ctxf: [qt 256][kf 64][lane][8]
// mbias is stored PRE-SCALED by log2(e): 0 / -30*log2e, so the exp path is
// a bare v_exp_f32 (exp2) with no per-element log2e multiply.
// ---------------------------------------------------------------------------

// ---------------------------------------------------------------------------
// Kernel T: prep. Converts weights + x to fragment-major bf16 via LDS tiles;
// mask -> float bias (log2-domain). Blocks: 0..95 Wq/Wk/Wv, 96..111 Wo,
// 112..175 xf, 176..191 mbias.
// ---------------------------------------------------------------------------
__global__ __launch_bounds__(256) void prep_weights(const float* __restrict__ x,
                                                    const float* __restrict__ Wq,
                                                    const float* __restrict__ Wk,
                                                    const float* __restrict__ Wv,
                                                    const float* __restrict__ Wo,
                                                    const int* __restrict__ mask,
                                                    bf16* __restrict__ Wqf,
                                                    bf16* __restrict__ Wkf,
                                                    bf16* __restrict__ Wvf,
                                                    bf16* __restrict__ Wof,
                                                    bf16* __restrict__ xf,
                                                    float* __restrict__ mbias) {
    __shared__ bf16 pw[16896];
    int bid = blockIdx.x, t = threadIdx.x;
    int lane = t & 63, wave = t >> 6;
    int lrow = lane & 15, quad = lane >> 4;

    if (bid < 96) {
        int m = bid >> 5, cg = bid & 31;
        const float* W = (m == 0) ? Wq : (m == 1) ? Wk : Wv;
        bf16* Wf       = (m == 0) ? Wqf : (m == 1) ? Wkf : Wvf;
        int slot = t & 15, rowb = t >> 4;
#pragma unroll
        for (int i = 0; i < 8; i++) {
            int r = rowb + i * 16;
            float4 v = *(const float4*)(W + (size_t)r * 2048 + cg * 64 + slot * 4);
            bf16x4 o; o[0]=(bf16)v.x; o[1]=(bf16)v.y; o[2]=(bf16)v.z; o[3]=(bf16)v.w;
            *(bf16x4*)(&pw[r * 68 + slot * 4]) = o;   // tile [k 128][col 64] stride 68
        }
        __syncthreads();
        int ctl = wave;
#pragma unroll
        for (int kf = 0; kf < 4; kf++) {
            bf16x8 w;
#pragma unroll
            for (int j = 0; j < 8; j++) w[j] = pw[(kf * 32 + quad * 8 + j) * 68 + ctl * 16 + lrow];
            *(bf16x8*)(Wf + (size_t)((cg * 4 + ctl) * 4 + kf) * 512 + lane * 8) = w;
        }
    } else if (bid < 112) {
        int kb16 = bid - 96, k0 = kb16 * 128;
        int slot = t & 31, rowb = t >> 5;
#pragma unroll
        for (int i = 0; i < 16; i++) {
            int r = rowb + i * 8;
            float4 v = *(const float4*)(Wo + (size_t)(k0 + r) * 128 + slot * 4);
            bf16x4 o; o[0]=(bf16)v.x; o[1]=(bf16)v.y; o[2]=(bf16)v.z; o[3]=(bf16)v.w;
            *(bf16x4*)(&pw[r * 132 + slot * 4]) = o;  // tile [k 128][col 128] stride 132
        }
        __syncthreads();
        int kfl = wave;
#pragma unroll
        for (int ct = 0; ct < 8; ct++) {
            bf16x8 w;
#pragma unroll
            for (int j = 0; j < 8; j++) w[j] = pw[(kfl * 32 + quad * 8 + j) * 132 + ct * 16 + lrow];
            *(bf16x8*)(Wof + (size_t)(ct * 64 + kb16 * 4 + kfl) * 512 + lane * 8) = w;
        }
    } else if (bid < 176) {
        int rg = bid - 112, r0 = rg * 64;
        int slot = t & 31, rowb = t >> 5;
#pragma unroll
        for (int i = 0; i < 8; i++) {
            int r = rowb + i * 8;
            float4 v = *(const float4*)(x + (size_t)(r0 + r) * 128 + slot * 4);
            bf16x4 o; o[0]=(bf16)v.x; o[1]=(bf16)v.y; o[2]=(bf16)v.z; o[3]=(bf16)v.w;
            *(bf16x4*)(&pw[r * 136 + slot * 4]) = o;  // tile [row 64][col 128] stride 136
        }
        __syncthreads();
        int rtl = wave;
#pragma unroll
        for (int kf = 0; kf < 4; kf++) {
            bf16x8 w = *(const bf16x8*)(&pw[(rtl * 16 + lrow) * 136 + kf * 32 + quad * 8]);
            *(bf16x8*)(xf + (size_t)((rg * 4 + rtl) * 4 + kf) * 512 + lane * 8) = w;
        }
    } else {
        int e = (bid - 176) * 256 + t;
        // log2-domain: exp2(-43.28) ~ 9e-14 ~ 0
        mbias[e] = mask[e] ? 0.0f : -43.2808512f;
    }
}

// ---------------------------------------------------------------------------
// Kernel A: Q/K/V projection, z split across blocks (grid (64,32,3)).
// All frag accesses coalesced; outputs Qf/Kf/Vf fragment-major.
// ---------------------------------------------------------------------------
__global__ __launch_bounds__(256) void qkv_proj(const bf16* __restrict__ xf,
                                                const float* __restrict__ bq,
                                                const float* __restrict__ bk,
                                                const float* __restrict__ bv,
                                                const bf16* __restrict__ Wqf,
                                                const bf16* __restrict__ Wkf,
                                                const bf16* __restrict__ Wvf,
                                                bf16* __restrict__ Qf,
                                                bf16* __restrict__ Kf,
                                                bf16* __restrict__ Vf) {
    __shared__ bf16 tile[64][72];

    int z = blockIdx.z;
    const float* bias = (z == 0) ? bq : (z == 1) ? bk : bv;
    const bf16*  Wf   = (z == 0) ? Wqf : (z == 1) ? Wkf : Wvf;

    int tid = threadIdx.x;
    int wave = tid >> 6, lane = tid & 63;
    int lrow = lane & 15, quad = lane >> 4;
    int r0b = blockIdx.x * 64;
    int c0 = blockIdx.y * 64;
    int cg4 = c0 >> 4;

    int rt = (r0b >> 4) + wave;
    bf16x8 a[4];
#pragma unroll
    for (int kf = 0; kf < 4; kf++)
        a[kf] = *(const bf16x8*)(xf + (size_t)(rt * 4 + kf) * 512 + lane * 8);

    int bb = r0b >> 11;
    int h  = c0 >> 7;
    int bhw = bb * 16 + h;
    int tile16 = (r0b & 2047) >> 4;
    int kbt = (r0b & 2047) >> 6;
    floatx4 zero4 = {0.f, 0.f, 0.f, 0.f};

    floatx4 acc[4] = {zero4, zero4, zero4, zero4};
#pragma unroll
    for (int kf = 0; kf < 4; kf++) {
#pragma unroll
        for (int nf = 0; nf < 4; nf++) {
            bf16x8 b = *(const bf16x8*)(Wf + (size_t)((cg4 + nf) * 4 + kf) * 512 + lane * 8);
            acc[nf] = MFMA32K(a[kf], b, acc[nf]);
        }
    }

#pragma unroll
    for (int nf = 0; nf < 4; nf++) {
        int col = nf * 16 + lrow;
        float bvv = bias[c0 + col];
#pragma unroll
        for (int r = 0; r < 4; r++) {
            int row = wave * 16 + quad * 4 + r;
            bf16 val = (bf16)(acc[nf][r] + bvv);
            if (z < 2) tile[row][col] = val;
            else       tile[col][row] = val;
        }
    }
    __syncthreads();

    if (z < 2) {
        bf16* dst = (z == 0) ? Qf : Kf;
        int s = wave;
        int kfbase = (c0 & 127) >> 5;
        size_t fbase = ((size_t)bhw * 128 + tile16 + s) * 4 + kfbase;
#pragma unroll
        for (int kfl = 0; kfl < 2; kfl++) {
            bf16x8 w = *(const bf16x8*)(&tile[s * 16 + lrow][kfl * 32 + quad * 8]);
            *(bf16x8*)(dst + (fbase + kfl) * 512 + lane * 8) = w;
        }
    } else {
        int nfl = wave;
        int nfbase = (c0 & 127) >> 4;
        size_t fbase = (((size_t)bhw * 32 + kbt) * 8 + (nfbase + nfl)) * 2;
#pragma unroll
        for (int g = 0; g < 2; g++) {
            bf16x4 a0 = *(const bf16x4*)(&tile[nfl * 16 + lrow][g * 32 + quad * 4]);
            bf16x4 a1 = *(const bf16x4*)(&tile[nfl * 16 + lrow][g * 32 + 16 + quad * 4]);
            bf16x8 w;
            w[0]=a0[0]; w[1]=a0[1]; w[2]=a0[2]; w[3]=a0[3];
            w[4]=a1[0]; w[5]=a1[1]; w[6]=a1[2]; w[7]=a1[3];
            *(bf16x8*)(Vf + (fbase + g) * 512 + lane * 8) = w;
        }
    }
}

// ---------------------------------------------------------------------------
// Kernel B: flash attention — R14 frozen structure (best measured: 89.1 µs,
// MfmaUtil 34%) + exp2 constant-folding: scale and mbias are pre-multiplied
// by log2(e), so the softmax exponent is a bare v_exp_f32 (saves 32
// v_mul_f32 per wave-iter on the busiest pipe).
// Reverted R15's split-K (occupancy didn't materialize; +17MB writes).
// ---------------------------------------------------------------------------
__global__ __launch_bounds__(256) void flash_attn(const bf16* __restrict__ Qf,
                                                  const bf16* __restrict__ Kf,
                                                  const bf16* __restrict__ Vf,
                                                  const float* __restrict__ mbias,
                                                  const int* __restrict__ mask,
                                                  bf16* __restrict__ ctxf) {
    __shared__ bf16 sm[36864];   // [0,32768): K/V dbuf; [32768,36864): mbias row (2048 f32)
    float* mbL = (float*)&sm[32768];

    int tid = threadIdx.x;
    int wave = tid >> 6, lane = tid & 63;
    int lrow = lane & 15, quad = lane >> 4;
    // XCD swizzle: 512 blocks = 8 xcd * (4 bh * 16 qblk)
    int bid = blockIdx.x;
    int xcd = bid & 7, seq = bid >> 3;          // seq 0..63
    int bh  = xcd * 4 + (seq >> 4);             // 0..31
    int qblk = seq & 15;                        // 0..15
    int b  = bh >> 4;
    int q0 = qblk * 128 + wave * 32;

    const float* mbp = mbias + b * N_;
    const bf16* kbase = Kf + (size_t)bh * 32 * 8192;
    const bf16* vbase = Vf + (size_t)bh * 32 * 8192;

    // Q B-frags from Qf (coalesced 16B loads), held all loop
    bf16x8 qf[2][4];
#pragma unroll
    for (int u = 0; u < 2; u++)
#pragma unroll
        for (int kf = 0; kf < 4; kf++)
            qf[u][kf] = *(const bf16x8*)(Qf + (size_t)(((size_t)bh * 128 + (q0 >> 4) + u) * 4 + kf) * 512 + lane * 8);

    bf16x8 ones;
#pragma unroll
    for (int j = 0; j < 8; j++) ones[j] = (bf16)1.0f;

    floatx4 zero4 = {0.f, 0.f, 0.f, 0.f};
    floatx4 O[2][8];
#pragma unroll
    for (int u = 0; u < 2; u++)
#pragma unroll
        for (int nf = 0; nf < 8; nf++) O[u][nf] = zero4;
    floatx4 Oext[2] = {zero4, zero4};   // row sums l[q] via ones-MFMA

    const float scale = 0.12751742f;    // (1/sqrt(128)) * log2(e)

    // ---- prologue: DMA tile 0 into buffer 0 + mbias row into LDS ----
#pragma unroll
    for (int i = 0; i < 4; i++) {
        int seg = wave * 4 + i;                // 0..15, 1KB each
        load_lds16(kbase + seg * 512 + lane * 8, &sm[seg * 512]);
        load_lds16(vbase + seg * 512 + lane * 8, &sm[8192 + seg * 512]);
    }
#pragma unroll
    for (int i = 0; i < 2; i++) {
        int seg = wave * 2 + i;                // 0..7, 256 floats (1KB) each
        load_lds16((const bf16*)(mbp + seg * 256) + lane * 8, (bf16*)(mbL + seg * 256));
    }

    for (int kb = 0; kb < 32; kb++) {
        int cur = (kb & 1) << 14;              // 0 or 16384

        // ---- 1./2. wait my DMA(kb) (+prologue mbias on kb==0), barrier ----
        __builtin_amdgcn_s_waitcnt(WAITCNT_VM(0));
        __builtin_amdgcn_s_barrier();

        // ---- 3. prefetch DMA(kb+1) into the other buffer ----
        if (kb < 31) {
            int nxt = cur ^ 16384;
            const bf16* ksrc = kbase + (size_t)(kb + 1) * 8192;
            const bf16* vsrc = vbase + (size_t)(kb + 1) * 8192;
#pragma unroll
            for (int i = 0; i < 4; i++) {
                int seg = wave * 4 + i;
                load_lds16(ksrc + seg * 512 + lane * 8, &sm[nxt + seg * 512]);
                load_lds16(vsrc + seg * 512 + lane * 8, &sm[nxt + 8192 + seg * 512]);
            }
        }

        // ---- 4. S^T per 16-key tile; exp2; pack into K=32 B-frags ----
        bf16x8 pf[2][2];
#pragma unroll
        for (int s = 0; s < 4; s++) {
            floatx4 S0 = zero4, S1 = zero4;
#pragma unroll
            for (int kf = 0; kf < 4; kf++) {
                bf16x8 kfr = *(const bf16x8*)(&sm[cur + ((s * 4 + kf) * 64 + lane) * 8]);
                S0 = MFMA32K(kfr, qf[0][kf], S0);
                S1 = MFMA32K(kfr, qf[1][kf], S1);
            }
            float4 mb4 = *(const float4*)(mbL + kb * 64 + s * 16 + quad * 4);  // LDS (lgkmcnt)
            const float* mbr = (const float*)&mb4;
            int g = s >> 1, o = (s & 1) * 4;
#pragma unroll
            for (int r = 0; r < 4; r++) {
                float p0 = __builtin_amdgcn_exp2f(fmaf(S0[r], scale, mbr[r]));
                float p1 = __builtin_amdgcn_exp2f(fmaf(S1[r], scale, mbr[r]));
                pf[0][g][o + r] = (bf16)p0;
                pf[1][g][o + r] = (bf16)p1;
            }
        }

        // ---- l row-sums via ones-MFMA ----
#pragma unroll
        for (int g = 0; g < 2; g++) {
            Oext[0] = MFMA32K(ones, pf[0][g], Oext[0]);
            Oext[1] = MFMA32K(ones, pf[1][g], Oext[1]);
        }

        // ---- PV: O^T[d][q] += V^T P, full-rate K=32 ----
#pragma unroll
        for (int nf = 0; nf < 8; nf++) {
#pragma unroll
            for (int g = 0; g < 2; g++) {
                bf16x8 vfr = *(const bf16x8*)(&sm[cur + 8192 + ((nf * 2 + g) * 64 + lane) * 8]);
                O[0][nf] = MFMA32K(vfr, pf[0][g], O[0][nf]);
                O[1][nf] = MFMA32K(vfr, pf[1][g], O[1][nf]);
            }
        }
        // no end-of-iter barrier: next iter's barrier (after vmcnt) protects
        // buf[nxt] — every wave reaching it has finished this iter's reads
    }

    // ---- epilogue: normalize, query-mask, reshape via LDS -> ctxf frags ----
    __syncthreads();                    // full drain before reusing sm
    const int* mp = mask + b * N_;
    int wb = wave * 4352;               // 32 rows * 136 stride per wave ([0,17408))
#pragma unroll
    for (int u = 0; u < 2; u++) {
        float lsum = Oext[u][0];
        int q = q0 + u * 16 + lrow;
        float rl = (mp[q] && lsum > 0.f) ? (1.0f / lsum) : 0.f;
#pragma unroll
        for (int nf = 0; nf < 8; nf++) {
            bf16x4 o;
#pragma unroll
            for (int j = 0; j < 4; j++) o[j] = (bf16)(O[u][nf][j] * rl);
            *(bf16x4*)(&sm[wb + (u * 16 + lrow) * 136 + nf * 16 + quad * 4]) = o;
        }
    }
    __syncthreads();
    int h4 = (bh & 15) * 4;
    size_t qtb = (size_t)b * 128 + (q0 >> 4);
#pragma unroll
    for (int u = 0; u < 2; u++) {
#pragma unroll
        for (int kfl = 0; kfl < 4; kfl++) {
            bf16x8 w = *(const bf16x8*)(&sm[wb + (u * 16 + lrow) * 136 + kfl * 32 + quad * 8]);
            *(bf16x8*)(ctxf + ((qtb + u) * 64 + h4 + kfl) * 512 + lane * 8) = w;
        }
    }
}

// ---------------------------------------------------------------------------
// Kernel C: out = ctx @ Wo + bo, fp32 out. SPLIT-K x2: 2 waves/block, wave w
// accumulates kf-half w, LDS-combine, wave 0 stores. Deterministic.
// ---------------------------------------------------------------------------
__global__ __launch_bounds__(128) void out_proj(const bf16* __restrict__ ctxf,
                                                const bf16* __restrict__ Wof,
                                                const float* __restrict__ bo,
                                                float* __restrict__ out) {
    __shared__ float red[512];         // wave1 partials: [nf2][r4][lane64]
    int tid = threadIdx.x;
    int wave = tid >> 6, lane = tid & 63;
    int lrow = lane & 15, quad = lane >> 4;
    int qt = blockIdx.x;               // 16-row tile
    int ct = blockIdx.y * 2;           // two 16-col tiles
    int r0 = qt * 16, c0 = ct * 16;

    floatx4 zero4 = {0.f, 0.f, 0.f, 0.f};
    floatx4 acc[2] = {zero4, zero4};
    const bf16* ap = ctxf + ((size_t)qt * 64 + wave * 32) * 512 + lane * 8;
    const bf16* b0 = Wof + ((size_t)ct * 64 + wave * 32) * 512 + lane * 8;
    const bf16* b1 = b0 + (size_t)64 * 512;
#pragma unroll 4
    for (int kf = 0; kf < 32; kf++) {
        bf16x8 a  = *(const bf16x8*)(ap + (size_t)kf * 512);
        bf16x8 w0 = *(const bf16x8*)(b0 + (size_t)kf * 512);
        bf16x8 w1 = *(const bf16x8*)(b1 + (size_t)kf * 512);
        acc[0] = MFMA32K(a, w0, acc[0]);
        acc[1] = MFMA32K(a, w1, acc[1]);
    }
    if (wave == 1) {
#pragma unroll
        for (int nf = 0; nf < 2; nf++)
#pragma unroll
            for (int r = 0; r < 4; r++)
                red[nf * 256 + r * 64 + lane] = acc[nf][r];
    }
    __syncthreads();
    if (wave == 0) {
#pragma unroll
        for (int nf = 0; nf < 2; nf++) {
            int col = c0 + nf * 16 + lrow;
            float bv = bo[col];
#pragma unroll
            for (int r = 0; r < 4; r++) {
                int m = r0 + quad * 4 + r;
                out[(size_t)m * 128 + col] = acc[nf][r] + red[nf * 256 + r * 64 + lane] + bv;
            }
        }
    }
}

// ---------------------------------------------------------------------------
extern "C" void kernel_launch(void* const* d_in, const int* in_sizes, int n_in,
                              void* d_out, int out_size, void* d_ws, size_t ws_size,
                              hipStream_t stream) {
    const float* x    = (const float*)d_in[0];
    const int*   mask = (const int*)d_in[1];
    const float* Wq   = (const float*)d_in[2];
    const float* bq   = (const float*)d_in[3];
    const float* Wk   = (const float*)d_in[4];
    const float* bk   = (const float*)d_in[5];
    const float* Wv   = (const float*)d_in[6];
    const float* bv   = (const float*)d_in[7];
    const float* Wo   = (const float*)d_in[8];
    const float* bo   = (const float*)d_in[9];
    float* out = (float*)d_out;

    char* ws = (char*)d_ws;
    size_t off = 0;
    bf16* Wqf = (bf16*)(ws + off); off += (size_t)262144 * 2;
    bf16* Wkf = (bf16*)(ws + off); off += (size_t)262144 * 2;
    bf16* Wvf = (bf16*)(ws + off); off += (size_t)262144 * 2;
    bf16* Wof = (bf16*)(ws + off); off += (size_t)262144 * 2;
    bf16* xf  = (bf16*)(ws + off); off += (size_t)524288 * 2;
    size_t qkv_elems = (size_t)BH_ * N_ * 128;           // 8.4M
    bf16* Qf  = (bf16*)(ws + off); off += qkv_elems * 2; // fragment-major
    bf16* Kf  = (bf16*)(ws + off); off += qkv_elems * 2;
    bf16* Vf  = (bf16*)(ws + off); off += qkv_elems * 2;
    bf16* ctxf = (bf16*)(ws + off); off += (size_t)M_ * ALL_ * 2;
    float* mbias = (float*)(ws + off); off += (size_t)B_ * N_ * 4;
    (void)ws_size; (void)in_sizes; (void)n_in; (void)out_size;

    prep_weights<<<192, 256, 0, stream>>>(x, Wq, Wk, Wv, Wo, mask,
                                          Wqf, Wkf, Wvf, Wof, xf, mbias);

    qkv_proj<<<dim3(64, 32, 3), 256, 0, stream>>>(xf, bq, bk, bv, Wqf, Wkf, Wvf,
                                                  Qf, Kf, Vf);

    flash_attn<<<512, 256, 0, stream>>>(Qf, Kf, Vf, mbias, mask, ctxf);

    out_proj<<<dim3(256, 4), 128, 0, stream>>>(ctxf, Wof, bo, out);
}

// Round 17
// 179.797 us; speedup vs baseline: 1.0871x; 1.0105x over previous
//
#include <hip/hip_runtime.h>
#include <hip/hip_bf16.h>

// Problem constants
#define B_   2
#define N_   2048
#define D_   128
#define H_   16
#define ALL_ 2048
#define M_   (B_*N_)    // 4096 total rows
#define BH_  (B_*H_)    // 32 (batch*heads)

typedef __bf16 bf16;
typedef __bf16 bf16x8 __attribute__((ext_vector_type(8)));
typedef __bf16 bf16x4 __attribute__((ext_vector_type(4)));
typedef float  floatx4 __attribute__((ext_vector_type(4)));

#define MFMA32K(a,b,c) __builtin_amdgcn_mfma_f32_16x16x32_bf16((a),(b),(c),0,0,0)

// async global->LDS DMA, 16B per lane (m97 pattern).
// Global address is PER-LANE (base + lane*8 bf16); LDS addr wave-uniform.
__device__ inline void load_lds16(const bf16* g, bf16* l) {
    __builtin_amdgcn_global_load_lds((const __attribute__((address_space(1))) void*)g,
                                     (__attribute__((address_space(3))) void*)l, 16, 0, 0);
}

#define WAITCNT_VM(n) ((0xF << 8) | (0x7 << 4) | (n))

// ---------------------------------------------------------------------------
// FRAGMENT-MAJOR LAYOUTS:
//  A/B-frag canonical (16x16x32): elem j of lane (lrow=lane&15,quad=lane>>4)
//    A[m=lrow][k=kf*32+quad*8+j]  /  B[k=kf*32+quad*8+j][n=lrow]
//  Wf  (Wq/Wk/Wv): [ct 128][kf 4][lane][8]  canonical
//  xf:  [rt 256][kf 4][lane][8]             canonical
//  Qf/Kf: [bh][t 128][kf 4][lane][8]        canonical
//  Vf:  [bh][kb 32][nf 8][g 2][lane][8]  PERMUTED k:
//        elem j = V[key=kb*64+(2g+(j>>2))*16+quad*4+(j&3)][d=nf*16+lrow]
//  ctxf: [qt 256][kf 64][lane][8]        PERMUTED k (same map over d):
//        elem j = ctx[q=qt*16+lrow][d' = (kf&3)*32+(j>>2)*16+quad*4+(j&3)]
//        (head = kf>>2) — written DIRECTLY from flash O accumulators
//        (concat of nf-pair floatx4s), no LDS reshape.
//  Wof: [ct 8][kf 64][lane][8]           PERMUTED k to MATCH ctxf:
//        elem j = Wo[k = kf*32+(j>>2)*16+quad*4+(j&3)][col=ct*16+lrow]
//  MFMA contraction is invariant when A and B agree on the k-permutation.
//  mbias pre-scaled by log2(e) (exp2 path).
// ---------------------------------------------------------------------------

// ---------------------------------------------------------------------------
// Kernel T: prep — finer grid (368 blocks, was 192: 0.75/CU was latency-
// naked). Blocks: 0..191 Wq/Wk/Wv (64 k-rows x 64 cols each), 192..223 Wo
// (128 k x 64 cols, PERMUTED pack), 224..351 xf (32 rows), 352..367 mbias.
// ---------------------------------------------------------------------------
__global__ __launch_bounds__(256) void prep_weights(const float* __restrict__ x,
                                                    const float* __restrict__ Wq,
                                                    const float* __restrict__ Wk,
                                                    const float* __restrict__ Wv,
                                                    const float* __restrict__ Wo,
                                                    const int* __restrict__ mask,
                                                    bf16* __restrict__ Wqf,
                                                    bf16* __restrict__ Wkf,
                                                    bf16* __restrict__ Wvf,
                                                    bf16* __restrict__ Wof,
                                                    bf16* __restrict__ xf,
                                                    float* __restrict__ mbias) {
    __shared__ bf16 pw[16896];
    int bid = blockIdx.x, t = threadIdx.x;
    int lane = t & 63, wave = t >> 6;
    int lrow = lane & 15, quad = lane >> 4;

    if (bid < 192) {
        // ---- Wq/Wk/Wv [128][2048]: block = 64 k-rows (half) x 64 cols ----
        int m = bid / 64, rest = bid % 64;
        int cg = rest >> 1, kh = rest & 1;
        const float* W = (m == 0) ? Wq : (m == 1) ? Wk : Wv;
        bf16* Wf       = (m == 0) ? Wqf : (m == 1) ? Wkf : Wvf;
        int slot = t & 15, rowb = t >> 4;
#pragma unroll
        for (int i = 0; i < 4; i++) {
            int rl_ = rowb + i * 16;           // local k-row 0..63
            float4 v = *(const float4*)(W + (size_t)(kh * 64 + rl_) * 2048 + cg * 64 + slot * 4);
            bf16x4 o; o[0]=(bf16)v.x; o[1]=(bf16)v.y; o[2]=(bf16)v.z; o[3]=(bf16)v.w;
            *(bf16x4*)(&pw[rl_ * 68 + slot * 4]) = o;   // tile [k 64][col 64] stride 68
        }
        __syncthreads();
        int ctl = wave;                        // local col-tile 0..3
#pragma unroll
        for (int kfl = 0; kfl < 2; kfl++) {
            bf16x8 w;
#pragma unroll
            for (int j = 0; j < 8; j++) w[j] = pw[(kfl * 32 + quad * 8 + j) * 68 + ctl * 16 + lrow];
            *(bf16x8*)(Wf + (size_t)((cg * 4 + ctl) * 4 + kh * 2 + kfl) * 512 + lane * 8) = w;
        }
    } else if (bid < 224) {
        // ---- Wo [2048][128]: block = 128 k-rows x 64-col half, PERMUTED ----
        int idx = bid - 192;
        int kb16 = idx >> 1, ch = idx & 1;
        int k0 = kb16 * 128;
        int slot = t & 15, rowb = t >> 4;
#pragma unroll
        for (int i = 0; i < 8; i++) {
            int r = rowb + i * 16;             // 0..127
            float4 v = *(const float4*)(Wo + (size_t)(k0 + r) * 128 + ch * 64 + slot * 4);
            bf16x4 o; o[0]=(bf16)v.x; o[1]=(bf16)v.y; o[2]=(bf16)v.z; o[3]=(bf16)v.w;
            *(bf16x4*)(&pw[r * 68 + slot * 4]) = o;     // tile [k 128][col 64] stride 68
        }
        __syncthreads();
        int ctl = wave;
        int ct = ch * 4 + ctl;
#pragma unroll
        for (int kfl = 0; kfl < 4; kfl++) {
            bf16x8 w;
            // PERMUTED k to match flash's O-concat A-frags:
            // elem j <- k = kfl*32 + (j>>2)*16 + quad*4 + (j&3)
#pragma unroll
            for (int j = 0; j < 8; j++)
                w[j] = pw[(kfl * 32 + ((j >> 2) << 4) + quad * 4 + (j & 3)) * 68 + ctl * 16 + lrow];
            *(bf16x8*)(Wof + (size_t)(ct * 64 + kb16 * 4 + kfl) * 512 + lane * 8) = w;
        }
    } else if (bid < 352) {
        // ---- x [4096][128] fp32 -> xf frags, 32 rows per block ----
        int idx = bid - 224, r0 = idx * 32;
        int slot = t & 31, rowb = t >> 5;
#pragma unroll
        for (int i = 0; i < 4; i++) {
            int r = rowb + i * 8;              // 0..31
            float4 v = *(const float4*)(x + (size_t)(r0 + r) * 128 + slot * 4);
            bf16x4 o; o[0]=(bf16)v.x; o[1]=(bf16)v.y; o[2]=(bf16)v.z; o[3]=(bf16)v.w;
            *(bf16x4*)(&pw[r * 136 + slot * 4]) = o;    // tile [row 32][col 128] stride 136
        }
        __syncthreads();
        int rtl = wave >> 1;                   // 2 row-tiles of 16
        int kf2 = (wave & 1) * 2;
#pragma unroll
        for (int kfl = 0; kfl < 2; kfl++) {
            int kf = kf2 + kfl;
            bf16x8 w = *(const bf16x8*)(&pw[(rtl * 16 + lrow) * 136 + kf * 32 + quad * 8]);
            *(bf16x8*)(xf + (size_t)((idx * 2 + rtl) * 4 + kf) * 512 + lane * 8) = w;
        }
    } else {
        int e = (bid - 352) * 256 + t;
        // log2-domain: exp2(-43.28) ~ 9e-14 ~ 0
        mbias[e] = mask[e] ? 0.0f : -43.2808512f;
    }
}

// ---------------------------------------------------------------------------
// Kernel A: Q/K/V projection, z split across blocks (grid (64,32,3)) —
// unchanged from R16.
// ---------------------------------------------------------------------------
__global__ __launch_bounds__(256) void qkv_proj(const bf16* __restrict__ xf,
                                                const float* __restrict__ bq,
                                                const float* __restrict__ bk,
                                                const float* __restrict__ bv,
                                                const bf16* __restrict__ Wqf,
                                                const bf16* __restrict__ Wkf,
                                                const bf16* __restrict__ Wvf,
                                                bf16* __restrict__ Qf,
                                                bf16* __restrict__ Kf,
                                                bf16* __restrict__ Vf) {
    __shared__ bf16 tile[64][72];

    int z = blockIdx.z;
    const float* bias = (z == 0) ? bq : (z == 1) ? bk : bv;
    const bf16*  Wf   = (z == 0) ? Wqf : (z == 1) ? Wkf : Wvf;

    int tid = threadIdx.x;
    int wave = tid >> 6, lane = tid & 63;
    int lrow = lane & 15, quad = lane >> 4;
    int r0b = blockIdx.x * 64;
    int c0 = blockIdx.y * 64;
    int cg4 = c0 >> 4;

    int rt = (r0b >> 4) + wave;
    bf16x8 a[4];
#pragma unroll
    for (int kf = 0; kf < 4; kf++)
        a[kf] = *(const bf16x8*)(xf + (size_t)(rt * 4 + kf) * 512 + lane * 8);

    int bb = r0b >> 11;
    int h  = c0 >> 7;
    int bhw = bb * 16 + h;
    int tile16 = (r0b & 2047) >> 4;
    int kbt = (r0b & 2047) >> 6;
    floatx4 zero4 = {0.f, 0.f, 0.f, 0.f};

    floatx4 acc[4] = {zero4, zero4, zero4, zero4};
#pragma unroll
    for (int kf = 0; kf < 4; kf++) {
#pragma unroll
        for (int nf = 0; nf < 4; nf++) {
            bf16x8 b = *(const bf16x8*)(Wf + (size_t)((cg4 + nf) * 4 + kf) * 512 + lane * 8);
            acc[nf] = MFMA32K(a[kf], b, acc[nf]);
        }
    }

#pragma unroll
    for (int nf = 0; nf < 4; nf++) {
        int col = nf * 16 + lrow;
        float bvv = bias[c0 + col];
#pragma unroll
        for (int r = 0; r < 4; r++) {
            int row = wave * 16 + quad * 4 + r;
            bf16 val = (bf16)(acc[nf][r] + bvv);
            if (z < 2) tile[row][col] = val;
            else       tile[col][row] = val;
        }
    }
    __syncthreads();

    if (z < 2) {
        bf16* dst = (z == 0) ? Qf : Kf;
        int s = wave;
        int kfbase = (c0 & 127) >> 5;
        size_t fbase = ((size_t)bhw * 128 + tile16 + s) * 4 + kfbase;
#pragma unroll
        for (int kfl = 0; kfl < 2; kfl++) {
            bf16x8 w = *(const bf16x8*)(&tile[s * 16 + lrow][kfl * 32 + quad * 8]);
            *(bf16x8*)(dst + (fbase + kfl) * 512 + lane * 8) = w;
        }
    } else {
        int nfl = wave;
        int nfbase = (c0 & 127) >> 4;
        size_t fbase = (((size_t)bhw * 32 + kbt) * 8 + (nfbase + nfl)) * 2;
#pragma unroll
        for (int g = 0; g < 2; g++) {
            bf16x4 a0 = *(const bf16x4*)(&tile[nfl * 16 + lrow][g * 32 + quad * 4]);
            bf16x4 a1 = *(const bf16x4*)(&tile[nfl * 16 + lrow][g * 32 + 16 + quad * 4]);
            bf16x8 w;
            w[0]=a0[0]; w[1]=a0[1]; w[2]=a0[2]; w[3]=a0[3];
            w[4]=a1[0]; w[5]=a1[1]; w[6]=a1[2]; w[7]=a1[3];
            *(bf16x8*)(Vf + (fbase + g) * 512 + lane * 8) = w;
        }
    }
}

// ---------------------------------------------------------------------------
// Kernel B: flash attention — R16 frozen K-loop + DIRECT-STORE epilogue:
// O is in C-layout (col=q, row=d=nf*16+quad*4+r); concatenating an nf-pair's
// normalized floatx4s IS a valid K=32 A-frag under the PV permutation
// (k=quad*8+j <-> d=(2g+(j>>2))*16+quad*4+(j&3)) — Wof is packed with the
// matching permutation in prep, so out_proj is unchanged. Deletes the
// epilogue LDS reshape: 2 barriers, 24 LDS ops/wave, all 196K conflict cyc.
// ---------------------------------------------------------------------------
__global__ __launch_bounds__(256) void flash_attn(const bf16* __restrict__ Qf,
                                                  const bf16* __restrict__ Kf,
                                                  const bf16* __restrict__ Vf,
                                                  const float* __restrict__ mbias,
                                                  const int* __restrict__ mask,
                                                  bf16* __restrict__ ctxf) {
    __shared__ bf16 sm[36864];   // [0,32768): K/V dbuf; [32768,36864): mbias row (2048 f32)
    float* mbL = (float*)&sm[32768];

    int tid = threadIdx.x;
    int wave = tid >> 6, lane = tid & 63;
    int lrow = lane & 15, quad = lane >> 4;
    // XCD swizzle: 512 blocks = 8 xcd * (4 bh * 16 qblk)
    int bid = blockIdx.x;
    int xcd = bid & 7, seq = bid >> 3;          // seq 0..63
    int bh  = xcd * 4 + (seq >> 4);             // 0..31
    int qblk = seq & 15;                        // 0..15
    int b  = bh >> 4;
    int q0 = qblk * 128 + wave * 32;

    const float* mbp = mbias + b * N_;
    const bf16* kbase = Kf + (size_t)bh * 32 * 8192;
    const bf16* vbase = Vf + (size_t)bh * 32 * 8192;

    // Q B-frags from Qf (coalesced 16B loads), held all loop
    bf16x8 qf[2][4];
#pragma unroll
    for (int u = 0; u < 2; u++)
#pragma unroll
        for (int kf = 0; kf < 4; kf++)
            qf[u][kf] = *(const bf16x8*)(Qf + (size_t)(((size_t)bh * 128 + (q0 >> 4) + u) * 4 + kf) * 512 + lane * 8);

    bf16x8 ones;
#pragma unroll
    for (int j = 0; j < 8; j++) ones[j] = (bf16)1.0f;

    floatx4 zero4 = {0.f, 0.f, 0.f, 0.f};
    floatx4 O[2][8];
#pragma unroll
    for (int u = 0; u < 2; u++)
#pragma unroll
        for (int nf = 0; nf < 8; nf++) O[u][nf] = zero4;
    floatx4 Oext[2] = {zero4, zero4};   // row sums l[q] via ones-MFMA

    const float scale = 0.12751742f;    // (1/sqrt(128)) * log2(e)

    // ---- prologue: DMA tile 0 into buffer 0 + mbias row into LDS ----
#pragma unroll
    for (int i = 0; i < 4; i++) {
        int seg = wave * 4 + i;                // 0..15, 1KB each
        load_lds16(kbase + seg * 512 + lane * 8, &sm[seg * 512]);
        load_lds16(vbase + seg * 512 + lane * 8, &sm[8192 + seg * 512]);
    }
#pragma unroll
    for (int i = 0; i < 2; i++) {
        int seg = wave * 2 + i;                // 0..7, 256 floats (1KB) each
        load_lds16((const bf16*)(mbp + seg * 256) + lane * 8, (bf16*)(mbL + seg * 256));
    }

    for (int kb = 0; kb < 32; kb++) {
        int cur = (kb & 1) << 14;              // 0 or 16384

        // ---- 1./2. wait my DMA(kb) (+prologue mbias on kb==0), barrier ----
        __builtin_amdgcn_s_waitcnt(WAITCNT_VM(0));
        __builtin_amdgcn_s_barrier();

        // ---- 3. prefetch DMA(kb+1) into the other buffer ----
        if (kb < 31) {
            int nxt = cur ^ 16384;
            const bf16* ksrc = kbase + (size_t)(kb + 1) * 8192;
            const bf16* vsrc = vbase + (size_t)(kb + 1) * 8192;
#pragma unroll
            for (int i = 0; i < 4; i++) {
                int seg = wave * 4 + i;
                load_lds16(ksrc + seg * 512 + lane * 8, &sm[nxt + seg * 512]);
                load_lds16(vsrc + seg * 512 + lane * 8, &sm[nxt + 8192 + seg * 512]);
            }
        }

        // ---- 4. S^T per 16-key tile; exp2; pack into K=32 B-frags ----
        bf16x8 pf[2][2];
#pragma unroll
        for (int s = 0; s < 4; s++) {
            floatx4 S0 = zero4, S1 = zero4;
#pragma unroll
            for (int kf = 0; kf < 4; kf++) {
                bf16x8 kfr = *(const bf16x8*)(&sm[cur + ((s * 4 + kf) * 64 + lane) * 8]);
                S0 = MFMA32K(kfr, qf[0][kf], S0);
                S1 = MFMA32K(kfr, qf[1][kf], S1);
            }
            float4 mb4 = *(const float4*)(mbL + kb * 64 + s * 16 + quad * 4);  // LDS (lgkmcnt)
            const float* mbr = (const float*)&mb4;
            int g = s >> 1, o = (s & 1) * 4;
#pragma unroll
            for (int r = 0; r < 4; r++) {
                float p0 = __builtin_amdgcn_exp2f(fmaf(S0[r], scale, mbr[r]));
                float p1 = __builtin_amdgcn_exp2f(fmaf(S1[r], scale, mbr[r]));
                pf[0][g][o + r] = (bf16)p0;
                pf[1][g][o + r] = (bf16)p1;
            }
        }

        // ---- l row-sums via ones-MFMA ----
#pragma unroll
        for (int g = 0; g < 2; g++) {
            Oext[0] = MFMA32K(ones, pf[0][g], Oext[0]);
            Oext[1] = MFMA32K(ones, pf[1][g], Oext[1]);
        }

        // ---- PV: O^T[d][q] += V^T P, full-rate K=32 ----
#pragma unroll
        for (int nf = 0; nf < 8; nf++) {
#pragma unroll
            for (int g = 0; g < 2; g++) {
                bf16x8 vfr = *(const bf16x8*)(&sm[cur + 8192 + ((nf * 2 + g) * 64 + lane) * 8]);
                O[0][nf] = MFMA32K(vfr, pf[0][g], O[0][nf]);
                O[1][nf] = MFMA32K(vfr, pf[1][g], O[1][nf]);
            }
        }
        // no end-of-iter barrier: next iter's barrier (after vmcnt) protects
        // buf[nxt] — every wave reaching it has finished this iter's reads
    }

    // ---- epilogue: normalize + DIRECT permuted-concat A-frag stores ----
    const int* mp = mask + b * N_;
    int h4 = (bh & 15) * 4;
    size_t qtb = (size_t)b * 128 + (q0 >> 4);
#pragma unroll
    for (int u = 0; u < 2; u++) {
        float lsum = Oext[u][0];
        int q = q0 + u * 16 + lrow;
        float rl = (mp[q] && lsum > 0.f) ? (1.0f / lsum) : 0.f;
#pragma unroll
        for (int g = 0; g < 4; g++) {
            bf16x8 w;
#pragma unroll
            for (int j = 0; j < 4; j++) {
                w[j]     = (bf16)(O[u][2 * g][j]     * rl);
                w[j + 4] = (bf16)(O[u][2 * g + 1][j] * rl);
            }
            *(bf16x8*)(ctxf + ((qtb + u) * 64 + h4 + g) * 512 + lane * 8) = w;
        }
    }
}

// ---------------------------------------------------------------------------
// Kernel C: out = ctx @ Wo + bo, fp32 out. SPLIT-K x2 (unchanged from R16;
// ctxf/Wof now carry a matching k-permutation, opaque to this kernel).
// ---------------------------------------------------------------------------
__global__ __launch_bounds__(128) void out_proj(const bf16* __restrict__ ctxf,
                                                const bf16* __restrict__ Wof,
                                                const float* __restrict__ bo,
                                                float* __restrict__ out) {
    __shared__ float red[512];         // wave1 partials: [nf2][r4][lane64]
    int tid = threadIdx.x;
    int wave = tid >> 6, lane = tid & 63;
    int lrow = lane & 15, quad = lane >> 4;
    int qt = blockIdx.x;               // 16-row tile
    int ct = blockIdx.y * 2;           // two 16-col tiles
    int r0 = qt * 16, c0 = ct * 16;

    floatx4 zero4 = {0.f, 0.f, 0.f, 0.f};
    floatx4 acc[2] = {zero4, zero4};
    const bf16* ap = ctxf + ((size_t)qt * 64 + wave * 32) * 512 + lane * 8;
    const bf16* b0 = Wof + ((size_t)ct * 64 + wave * 32) * 512 + lane * 8;
    const bf16* b1 = b0 + (size_t)64 * 512;
#pragma unroll 4
    for (int kf = 0; kf < 32; kf++) {
        bf16x8 a  = *(const bf16x8*)(ap + (size_t)kf * 512);
        bf16x8 w0 = *(const bf16x8*)(b0 + (size_t)kf * 512);
        bf16x8 w1 = *(const bf16x8*)(b1 + (size_t)kf * 512);
        acc[0] = MFMA32K(a, w0, acc[0]);
        acc[1] = MFMA32K(a, w1, acc[1]);
    }
    if (wave == 1) {
#pragma unroll
        for (int nf = 0; nf < 2; nf++)
#pragma unroll
            for (int r = 0; r < 4; r++)
                red[nf * 256 + r * 64 + lane] = acc[nf][r];
    }
    __syncthreads();
    if (wave == 0) {
#pragma unroll
        for (int nf = 0; nf < 2; nf++) {
            int col = c0 + nf * 16 + lrow;
            float bv = bo[col];
#pragma unroll
            for (int r = 0; r < 4; r++) {
                int m = r0 + quad * 4 + r;
                out[(size_t)m * 128 + col] = acc[nf][r] + red[nf * 256 + r * 64 + lane] + bv;
            }
        }
    }
}

// ---------------------------------------------------------------------------
extern "C" void kernel_launch(void* const* d_in, const int* in_sizes, int n_in,
                              void* d_out, int out_size, void* d_ws, size_t ws_size,
                              hipStream_t stream) {
    const float* x    = (const float*)d_in[0];
    const int*   mask = (const int*)d_in[1];
    const float* Wq   = (const float*)d_in[2];
    const float* bq   = (const float*)d_in[3];
    const float* Wk   = (const float*)d_in[4];
    const float* bk   = (const float*)d_in[5];
    const float* Wv   = (const float*)d_in[6];
    const float* bv   = (const float*)d_in[7];
    const float* Wo   = (const float*)d_in[8];
    const float* bo   = (const float*)d_in[9];
    float* out = (float*)d_out;

    char* ws = (char*)d_ws;
    size_t off = 0;
    bf16* Wqf = (bf16*)(ws + off); off += (size_t)262144 * 2;
    bf16* Wkf = (bf16*)(ws + off); off += (size_t)262144 * 2;
    bf16* Wvf = (bf16*)(ws + off); off += (size_t)262144 * 2;
    bf16* Wof = (bf16*)(ws + off); off += (size_t)262144 * 2;
    bf16* xf  = (bf16*)(ws + off); off += (size_t)524288 * 2;
    size_t qkv_elems = (size_t)BH_ * N_ * 128;           // 8.4M
    bf16* Qf  = (bf16*)(ws + off); off += qkv_elems * 2; // fragment-major
    bf16* Kf  = (bf16*)(ws + off); off += qkv_elems * 2;
    bf16* Vf  = (bf16*)(ws + off); off += qkv_elems * 2;
    bf16* ctxf = (bf16*)(ws + off); off += (size_t)M_ * ALL_ * 2;
    float* mbias = (float*)(ws + off); off += (size_t)B_ * N_ * 4;
    (void)ws_size; (void)in_sizes; (void)n_in; (void)out_size;

    prep_weights<<<368, 256, 0, stream>>>(x, Wq, Wk, Wv, Wo, mask,
                                          Wqf, Wkf, Wvf, Wof, xf, mbias);

    qkv_proj<<<dim3(64, 32, 3), 256, 0, stream>>>(xf, bq, bk, bv, Wqf, Wkf, Wvf,
                                                  Qf, Kf, Vf);

    flash_attn<<<512, 256, 0, stream>>>(Qf, Kf, Vf, mbias, mask, ctxf);

    out_proj<<<dim3(256, 4), 128, 0, stream>>>(ctxf, Wof, bo, out);
}